// Round 1
// 77.581 us; speedup vs baseline: 1.0340x; 1.0340x over previous
//
#include <hip/hip_runtime.h>

// Factorized NaiveBias2d:
//   out[n, a*32+b, h, d] = sum_e bias[h,b,e]*Vc[n,e,h,d] + sum_c bias[h,a,c]*Ve[n,c,h,d]
//   bias[h,j,i] = w[h, (32 + j - i) % 63]
//   Vc[n,e,h,d] = sum_c v[n, c*32+e, h, d]   Ve[n,c,h,d] = sum_e v[n, c*32+e, h, d]
//
// Constants: BATCH=8, SEQ=1024 (32x32), HEADS=8, DIM=64 -> hd stride 512 floats
// = 128 float4.
//
// v2: terms+out fused into one kernel at (n,h,a-pair) granularity.
//   - old terms_kernel ran 64 blocks (1 wave/SIMD on 64 CUs) and round-tripped
//     T1/T2 (1 MB) through global; old out_kernel was a 3rd launch re-reading it.
//   - fused kernel: 1024 blocks (4/CU), T1 lives in LDS (8 KB), T2 rows in LDS
//     (0.5 KB). T1 matmul recomputed per a-pair block: 131 kFLOP -> free.

#define S 32
#define HD4 128   // hd extent in float4 units

// ---------------- Stage 1: reductions over c (Vc) and e (Ve) ----------------
// grid 512 blocks x 128 threads (float4 per thread over hd).
// Blocks 0..255: Vc (block=n*32+e). Blocks 256..511: Ve (block=n*32+c).
// Each wave-load is 64 lanes x 16 B = 1 KiB contiguous (coalescing sweet spot).
__global__ __launch_bounds__(128) void reduce_kernel(
    const float4* __restrict__ v, float4* __restrict__ Vc,
    float4* __restrict__ Ve) {
  int block = blockIdx.x;
  int t = threadIdx.x;                  // 0..127
  bool isVc = block < 256;
  int b2 = isVc ? block : block - 256;  // n*32 + x
  int n = b2 >> 5;
  int x = b2 & 31;                      // e for Vc, c for Ve
  const float4* base = v + (size_t)n * 1024 * HD4 + t;
  float4 acc = make_float4(0.f, 0.f, 0.f, 0.f);
  if (isVc) {
#pragma unroll
    for (int c = 0; c < 32; ++c) {
      float4 r = base[(size_t)(c * S + x) * HD4];
      acc.x += r.x; acc.y += r.y; acc.z += r.z; acc.w += r.w;
    }
    Vc[(size_t)b2 * HD4 + t] = acc;
  } else {
#pragma unroll
    for (int e = 0; e < 32; ++e) {
      float4 r = base[(size_t)(x * S + e) * HD4];
      acc.x += r.x; acc.y += r.y; acc.z += r.z; acc.w += r.w;
    }
    Ve[(size_t)b2 * HD4 + t] = acc;
  }
}

// ---------------- Stage 2: fused terms + out ----------------
// grid 1024 blocks: blk = (n*8 + h)*16 + a2, a2 handles a in {2*a2, 2*a2+1}.
// 256 threads. Per block:
//   stage bias (4 KB) + Vc/Ve tiles (16 KB, L2-resident source),
//   T1[b][d] = sum_e bias[b][e]*Vc[e][d]  -> LDS (recomputed per a-pair, cheap)
//   t2[ar][d] = sum_c bias[a][c]*Ve[c][d] -> LDS
//   out[n, a*32+b, h, :] = T1[b][:] + t2[ar][:]   (float4 stores, 256 B/row seg)
__global__ __launch_bounds__(256) void fused_kernel(
    const float* __restrict__ w,
    const float* __restrict__ Vc, const float* __restrict__ Ve,
    float4* __restrict__ out) {
  __shared__ float bias_s[32][32];
  __shared__ float vc_s[32][64];
  __shared__ float ve_s[32][64];
  __shared__ float t1_s[32][68];   // +4 pad: break same-bank rows for b128 reads
  __shared__ float t2_s[2][68];

  int blk = blockIdx.x;
  int a0 = (blk & 15) << 1;
  int nh = blk >> 4;
  int n = nh >> 3, h = nh & 7;
  int t = threadIdx.x;

  // bias[b][e] = w[h, (32 + b - e) % 63]; (32+b-e) in [1,63], %63 -> [0,62]
  for (int idx = t; idx < 1024; idx += 256) {
    int b = idx >> 5, e = idx & 31;
    bias_s[b][e] = w[h * 63 + (32 + b - e) % 63];
  }
  // Stage Vc/Ve tiles for this (n,h): 32 rows x 16 float4 each (L2 hits).
  for (int idx = t; idx < 512; idx += 256) {
    int e = idx >> 4, d4 = idx & 15;
    size_t g = ((size_t)(n * S + e) * 8 + h) * 16 + d4;  // float4 units
    float4 A = ((const float4*)Vc)[g];
    float4 B = ((const float4*)Ve)[g];
    *(float4*)(&vc_s[e][d4 * 4]) = A;
    *(float4*)(&ve_s[e][d4 * 4]) = B;
  }
  __syncthreads();

  int d = t & 63;    // lanes of a wave share bg -> bias_s reads broadcast
  int bg = t >> 6;   // 0..3
  for (int b = bg; b < 32; b += 4) {
    float acc = 0.f;
#pragma unroll
    for (int e = 0; e < 32; ++e) acc += bias_s[b][e] * vc_s[e][d];
    t1_s[b][d] = acc;
  }
  if (bg < 2) {      // waves 0,1 compute the two T2 rows for a0, a0+1
    float acc = 0.f;
#pragma unroll
    for (int c = 0; c < 32; ++c) acc += bias_s[a0 + bg][c] * ve_s[c][d];
    t2_s[bg][d] = acc;
  }
  __syncthreads();

  // Write 2 x 32 x 64 floats = 16 KB per block as float4.
#pragma unroll
  for (int ar = 0; ar < 2; ++ar) {
    int a = a0 + ar;
#pragma unroll
    for (int it = 0; it < 2; ++it) {
      int idx = it * 256 + t;          // 0..511
      int b = idx >> 4, d4 = idx & 15;
      float4 x = *(const float4*)(&t1_s[b][d4 * 4]);
      float4 y = *(const float4*)(&t2_s[ar][d4 * 4]);
      out[((size_t)(n * 1024 + a * S + b) * 8 + h) * 16 + d4] =
          make_float4(x.x + y.x, x.y + y.y, x.z + y.z, x.w + y.w);
    }
  }
}

extern "C" void kernel_launch(void* const* d_in, const int* in_sizes, int n_in,
                              void* d_out, int out_size, void* d_ws, size_t ws_size,
                              hipStream_t stream) {
  const float* v = (const float*)d_in[0];   // (8,1024,8,64) fp32
  const float* w = (const float*)d_in[1];   // (1,8,63)      fp32
  float* out = (float*)d_out;               // (8,1024,8,64) fp32
  float* ws  = (float*)d_ws;

  float* Vc = ws;                 // 131072 floats
  float* Ve = ws + 131072;        // 131072   (1 MB total)

  reduce_kernel<<<512, 128, 0, stream>>>((const float4*)v, (float4*)Vc,
                                         (float4*)Ve);
  fused_kernel<<<1024, 256, 0, stream>>>(w, Vc, Ve, (float4*)out);
}